// Round 13
// baseline (659.829 us; speedup 1.0000x reference)
//
#include <hip/hip_runtime.h>

// FSAS slab pipeline, 4 slabs of 64 rows, bf16 intermediates.
//   k2 v7: LDS-staged xp + out-ch split (grid.z = b*2+half), wave = 48 ch
//          (3x acc[16]), readfirstlane(wv) for scalar weight path. ~59 us/slab.
//   k3 v2: 32-row x 64-col tiles. ~35 us/slab.
//   kC v4: q STREAMED per-iy (1 uint4/row) instead of q[64] preloaded:
//          cuts ~56 unified regs from the conv-phase peak (~200 -> ~130).
//          Round-12 build showed identical-source kC swing to VGPR 128 /
//          occ 19% / 70us — pressure at the allocator cliff; remove it.
//          Accumulation order bitwise-identical. Keep bounds-2 (bounds-3
//          spills: round-11, WRITE 16->117 MB).
// Workspace:
//   kv  fp32 @ 0      (512)
//   whT fp32 @ 512    (24576)  whT[c*384+o] = w_hidden[o][c]
//   wpT fp32 @ 25088  (8192)   wpT[c*64+o]  = w_proj[o][c]
//   hid bf16 @ float-ofs 40960 : [4][384][66][256]  (51.9 MB)
//   qkv bf16 after hid          : [4][384][256][64]  (50.3 MB)
// Total 102,400,000 B = 97.66 MiB (< proven 99.15 MiB).

#define HW    65536
#define SLAB  64
#define HROWS 66
#define HSZ2  (HROWS*256)   // bf16 elems per (b,ch) hid plane
#define QS    16384         // bf16 elems per (b,ch) qkv plane (256 patches * 64)

__device__ __forceinline__ unsigned short f2bf(float f) {
    unsigned u = __float_as_uint(f);
    u += 0x7FFFu + ((u >> 16) & 1u);       // RNE
    return (unsigned short)(u >> 16);
}
__device__ __forceinline__ float bflo(unsigned u) { return __uint_as_float(u << 16); }
__device__ __forceinline__ float bfhi(unsigned u) { return __uint_as_float(u & 0xFFFF0000u); }

__global__ void k_prep(const float* __restrict__ prior, const float* __restrict__ wk,
                       const float* __restrict__ wh, const float* __restrict__ wp,
                       float* __restrict__ kv, float* __restrict__ whT, float* __restrict__ wpT) {
    int t = blockIdx.x * 256 + threadIdx.x;
    if (t < 512) {
        int b = t >> 7, k = t & 127;
        const float* p = prior + b * 192;
        const float* w = wk + k * 192;
        float s = 0.f;
        for (int f = 0; f < 192; ++f) s = fmaf(p[f], w[f], s);
        kv[t] = s;
        return;
    }
    t -= 512;
    if (t < 24576) {
        int c = t / 384, o = t - c * 384;
        whT[t] = wh[o * 64 + c];
        return;
    }
    t -= 24576;
    int c = t >> 6, o = t & 63;
    wpT[t] = wp[o * 128 + c];
}

// v7: block = (row, col-quarter, b*2+half). Stage xp[64ch][64px] in LDS (affine
// fused, coalesced float2), then wave wv (readfirstlane -> SGPR) computes
// out-ch half*192 + wv*48 .. +47 in 3 iters of acc[16]. Weights scalar-loaded.
__global__ __launch_bounds__(256, 4) void k2_hidden(const float* __restrict__ x,
    const float* __restrict__ whT, const float* __restrict__ kv,
    unsigned short* __restrict__ hid, int r0) {
    __shared__ float sXp[64 * 64];   // 16 KB
    int t = threadIdx.x;
    int row = blockIdx.x;            // 0..65
    int colq = blockIdx.y;           // 0..3
    int z = blockIdx.z;              // 0..7
    int b = z >> 1;
    int half = z & 1;
    int col0 = colq * 64;
    int g = r0 - 1 + row;
    int px = t & 63;
    int wv = __builtin_amdgcn_readfirstlane(t >> 6);   // SGPR -> scalar weight path
    int och0 = half * 192 + wv * 48;
    unsigned short* hb = hid + ((size_t)(b * 384 + och0)) * HSZ2
                         + row * 256 + col0 + px;
    if (g < 0 || g > 255) {          // block-uniform edge path (no barrier here)
        #pragma unroll
        for (int it = 0; it < 3; ++it)
            #pragma unroll
            for (int j = 0; j < 16; ++j)
                hb[(size_t)(it * 16 + j) * HSZ2] = 0;
        return;
    }
    const float* kv1 = kv + b * 128;
    const float* kv2 = kv1 + 64;
    const float2* xb = (const float2*)(x + (size_t)b * 64 * HW + (size_t)g * 256 + col0);
    #pragma unroll
    for (int i = 0; i < 8; ++i) {    // 2048 float2 = 64ch x 32
        int idx = t + i * 256;
        int c = idx >> 5;            // 0..63
        int l2 = idx & 31;
        float2 xv = xb[(size_t)c * (HW / 2) + l2];
        float2 s;
        s.x = fmaf(xv.x, kv1[c], kv2[c]);
        s.y = fmaf(xv.y, kv1[c], kv2[c]);
        *(float2*)&sXp[c * 64 + l2 * 2] = s;
    }
    __syncthreads();
    #pragma unroll
    for (int it = 0; it < 3; ++it) {
        const float* wbase = whT + och0 + it * 16;   // SGPR-uniform
        float acc[16];
        #pragma unroll
        for (int j = 0; j < 16; ++j) acc[j] = 0.f;
        #pragma unroll 4
        for (int c = 0; c < 64; ++c) {
            float xv = sXp[c * 64 + px];
            const float* wr = wbase + c * 384;       // wave-uniform -> scalar loads
            #pragma unroll
            for (int j = 0; j < 16; ++j)
                acc[j] = fmaf(wr[j], xv, acc[j]);
        }
        #pragma unroll
        for (int j = 0; j < 16; ++j)
            hb[(size_t)(it * 16 + j) * HSZ2] = f2bf(acc[j]);
    }
}

// grouped 3x3 conv from bf16 hid -> bf16 qkv patchified [ch][patch][py*8+px]
// v2: 32-row x 64-col tile per block (halo 34x66), 4 pp-passes, 288 fma/thread.
__global__ __launch_bounds__(256) void k3_dw(const unsigned short* __restrict__ hid,
    const float* __restrict__ wdw, unsigned short* __restrict__ qkv) {
    __shared__ float sIn[2 * 34 * 66];
    int t = threadIdx.x;
    int bid = blockIdx.x;            // 8 tiles: tx 0..3 (x64 cols), ty 0..1 (x32 rows)
    int gl = blockIdx.y;             // 0..191
    int b = blockIdx.z;
    int tx = bid & 3, ty = bid >> 2;
    int x0 = tx * 64, y0 = ty * 32;
    const unsigned short* hbase = hid + ((size_t)(b * 384 + 2 * gl)) * HSZ2;
    for (int idx = t; idx < 2 * 34 * 66; idx += 256) {
        int chl = idx >= 2244;
        int rem = idx - chl * 2244;
        int row = rem / 66;
        int col = rem - row * 66;
        int gx = x0 + col - 1;
        float v = 0.f;
        if (gx >= 0 && gx < 256)
            v = bflo((unsigned)hbase[(size_t)chl * HSZ2 + (y0 + row) * 256 + gx]);
        sIn[idx] = v;
    }
    __syncthreads();
    int og = 2 * gl;
    float w0[18], w1[18];
    #pragma unroll
    for (int i = 0; i < 18; ++i) {
        w0[i] = wdw[(size_t)og * 18 + i];
        w1[i] = wdw[(size_t)(og + 1) * 18 + i];
    }
    unsigned short* q0 = qkv + ((size_t)(b * 384 + og)) * QS;
    #pragma unroll
    for (int pp = 0; pp < 4; ++pp) {
        int ly = pp * 8 + (t >> 5);                  // 0..31
        int lxp = (t & 31) * 2;                      // even col in tile
        float a[2][2];                               // [px][out-ch]
        #pragma unroll
        for (int px = 0; px < 2; ++px) {
            float s0 = 0.f, s1 = 0.f;
            #pragma unroll
            for (int i = 0; i < 2; ++i)
                #pragma unroll
                for (int ky = 0; ky < 3; ++ky)
                    #pragma unroll
                    for (int kx = 0; kx < 3; ++kx) {
                        float v = sIn[i * 2244 + (ly + ky) * 66 + (lxp + px + kx)];
                        s0 = fmaf(w0[i * 9 + ky * 3 + kx], v, s0);
                        s1 = fmaf(w1[i * 9 + ky * 3 + kx], v, s1);
                    }
            a[px][0] = s0; a[px][1] = s1;
        }
        int row = y0 + ly;                           // slab row 0..63
        int gx = x0 + lxp;
        int patch = (row >> 3) * 32 + (gx >> 3);     // 0..255
        int off = patch * 64 + (row & 7) * 8 + (gx & 7);   // even
        ((unsigned*)(q0 + off))[0] =
            (unsigned)f2bf(a[0][0]) | ((unsigned)f2bf(a[1][0]) << 16);
        ((unsigned*)(q0 + QS + off))[0] =
            (unsigned)f2bf(a[0][1]) | ((unsigned)f2bf(a[1][1]) << 16);
    }
}

// Fused per-patch: circular conv + LN(128) + *v + proj 128->64.
// Thread t: channel c = t&127, py-half pyh = t>>7.
// v4: q streamed per-iy (k[64] held pre-rotated); 3 barriers, no serial phase.
//   P0 conv -> sC[c][68] (float4 writes, transposed)
//   P1 reduce over c: (q4,px) mapping, 2x shfl_xor -> sMu/sRstd
//   P3 normalize from acc regs -> tvv to sT[pix][132] (aliases sC)
//   P4 proj: ds_read_b128 over channels (4/instr), weights via SGPR
__global__ __launch_bounds__(256, 2) void kC_patch(const unsigned short* __restrict__ qkv,
    const float* __restrict__ wpT, const float* __restrict__ lnw,
    const float* __restrict__ lnb, float* __restrict__ outp, int r0) {
    __shared__ __align__(16) float sBuf[128 * 68];   // P0/P1: sC[c][68]; P3/P4: sT[pix][132]
    __shared__ __align__(16) float sMu[64];
    __shared__ __align__(16) float sRstd[64];
    int t = threadIdx.x;
    int p = blockIdx.x;              // slab-local patch 0..255
    int b = blockIdx.y;
    int c = t & 127;
    int pyh = t >> 7;

    const uint4* gq = (const uint4*)(qkv + ((size_t)(b * 384 + c)) * QS + p * 64);
    const uint4* gk = (const uint4*)(qkv + ((size_t)(b * 384 + 128 + c)) * QS + p * 64);
    // k rows pre-rotated: reg row s = global row (s + 4*pyh)&7 ; one uint4 per row
    float k[64];
    #pragma unroll
    for (int s = 0; s < 8; ++s) {
        int r = (s + 4 * pyh) & 7;
        uint4 u = gk[r];
        k[s * 8 + 0] = bflo(u.x); k[s * 8 + 1] = bfhi(u.x);
        k[s * 8 + 2] = bflo(u.y); k[s * 8 + 3] = bfhi(u.y);
        k[s * 8 + 4] = bflo(u.z); k[s * 8 + 5] = bfhi(u.z);
        k[s * 8 + 6] = bflo(u.w); k[s * 8 + 7] = bfhi(u.w);
    }
    float acc[4][8];
    #pragma unroll
    for (int it = 0; it < 4; ++it)
        #pragma unroll
        for (int px = 0; px < 8; ++px) acc[it][px] = 0.f;
    // conv: stream one q-row (8 bf16 = 1 uint4) per iy — peak regs ~130 not ~200.
    // Same iy->ix->it->px order as v2 -> bitwise-identical accumulation.
    #pragma unroll
    for (int iy = 0; iy < 8; ++iy) {
        uint4 uq = gq[iy];
        float qr[8];
        qr[0] = bflo(uq.x); qr[1] = bfhi(uq.x);
        qr[2] = bflo(uq.y); qr[3] = bfhi(uq.y);
        qr[4] = bflo(uq.z); qr[5] = bfhi(uq.z);
        qr[6] = bflo(uq.w); qr[7] = bfhi(uq.w);
        #pragma unroll
        for (int ix = 0; ix < 8; ++ix) {
            float qv = qr[ix];
            #pragma unroll
            for (int it = 0; it < 4; ++it) {
                int ks = (it - iy) & 7;              // compile-time
                #pragma unroll
                for (int px = 0; px < 8; ++px)
                    acc[it][px] = fmaf(qv, k[ks * 8 + ((px - ix) & 7)], acc[it][px]);
            }
        }
    }
    // transposed conv scratch: sC[c][pix], pad 68 (row stride 272 B, 16B-aligned)
    #pragma unroll
    for (int it = 0; it < 4; ++it) {
        int pix0 = pyh * 32 + it * 8;
        *(float4*)&sBuf[c * 68 + pix0] =
            make_float4(acc[it][0], acc[it][1], acc[it][2], acc[it][3]);
        *(float4*)&sBuf[c * 68 + pix0 + 4] =
            make_float4(acc[it][4], acc[it][5], acc[it][6], acc[it][7]);
    }
    // prefetch v (32 bf16 = 4 uint4)
    const uint4* gv = (const uint4*)(qkv + ((size_t)(b * 384 + 256 + c)) * QS
                                     + p * 64 + pyh * 32);
    float vv[32];
    #pragma unroll
    for (int f = 0; f < 4; ++f) {
        uint4 u = gv[f];
        vv[f * 8 + 0] = bflo(u.x); vv[f * 8 + 1] = bfhi(u.x);
        vv[f * 8 + 2] = bflo(u.y); vv[f * 8 + 3] = bfhi(u.y);
        vv[f * 8 + 4] = bflo(u.z); vv[f * 8 + 5] = bfhi(u.z);
        vv[f * 8 + 6] = bflo(u.w); vv[f * 8 + 7] = bfhi(u.w);
    }
    float lw = lnw[c], lb = lnb[c];
    __syncthreads();

    // P1: per-pixel channel reduction. Wave w owns pixels w*16..w*16+15;
    // lane bits 4..5 = channel-quarter -> butterfly within the wave.
    {
        int q4 = (t >> 4) & 3;
        int px = (t & 15) | ((t >> 6) << 4);
        float s = 0.f, s2 = 0.f;
        #pragma unroll
        for (int j = 0; j < 32; ++j) {
            float v = sBuf[(q4 * 32 + j) * 68 + px];
            s += v;
            s2 = fmaf(v, v, s2);
        }
        s  += __shfl_xor(s, 16);   s2 += __shfl_xor(s2, 16);
        s  += __shfl_xor(s, 32);   s2 += __shfl_xor(s2, 32);
        if ((t & 48) == 0) {
            float mu = s * (1.f / 128.f);
            float var = s2 * (1.f / 128.f) - mu * mu;
            sMu[px] = mu;
            sRstd[px] = rsqrtf(var + 1e-5f);
        }
    }
    __syncthreads();
    // P3: normalize from acc regs, * v, stage tvv as sT[pix][132] (c contiguous)
    #pragma unroll
    for (int it = 0; it < 4; ++it) {
        int pix0 = pyh * 32 + it * 8;
        float4 ma = *(const float4*)&sMu[pix0];
        float4 mb = *(const float4*)&sMu[pix0 + 4];
        float4 ra = *(const float4*)&sRstd[pix0];
        float4 rb = *(const float4*)&sRstd[pix0 + 4];
        float mus[8] = {ma.x, ma.y, ma.z, ma.w, mb.x, mb.y, mb.z, mb.w};
        float rss[8] = {ra.x, ra.y, ra.z, ra.w, rb.x, rb.y, rb.z, rb.w};
        #pragma unroll
        for (int px = 0; px < 8; ++px) {
            float tv = fmaf((acc[it][px] - mus[px]) * rss[px], lw, lb)
                       * vv[it * 8 + px];
            sBuf[(pix0 + px) * 132 + c] = tv;
        }
    }
    __syncthreads();
    // P4: proj 128->64, tvv read as float4 (4 channels / ds_read_b128)
    {
        int px = t & 63;
        int og = __builtin_amdgcn_readfirstlane((t >> 6) * 16);
        float po[16];
        #pragma unroll
        for (int j = 0; j < 16; ++j) po[j] = 0.f;
        const float4* tb = (const float4*)&sBuf[px * 132];
        #pragma unroll 4
        for (int k4 = 0; k4 < 32; ++k4) {
            float4 tv = tb[k4];
            const float* w0 = wpT + (k4 * 4 + 0) * 64 + og;
            const float* w1 = wpT + (k4 * 4 + 1) * 64 + og;
            const float* w2 = wpT + (k4 * 4 + 2) * 64 + og;
            const float* w3 = wpT + (k4 * 4 + 3) * 64 + og;
            #pragma unroll
            for (int j = 0; j < 16; ++j)
                po[j] = fmaf(w0[j], tv.x,
                        fmaf(w1[j], tv.y,
                        fmaf(w2[j], tv.z,
                        fmaf(w3[j], tv.w, po[j]))));
        }
        int grow = r0 + (p >> 5) * 8 + (px >> 3);
        int gcol = (p & 31) * 8 + (px & 7);
        float* ob = outp + ((size_t)(b * 64 + og)) * HW + grow * 256 + gcol;
        #pragma unroll
        for (int j = 0; j < 16; ++j) ob[(size_t)j * HW] = po[j];
    }
}

extern "C" void kernel_launch(void* const* d_in, const int* in_sizes, int n_in,
                              void* d_out, int out_size, void* d_ws, size_t ws_size,
                              hipStream_t stream) {
    const float* x     = (const float*)d_in[0];
    const float* prior = (const float*)d_in[1];
    const float* wk    = (const float*)d_in[2];
    const float* wh    = (const float*)d_in[3];
    const float* wdw   = (const float*)d_in[4];
    const float* wp    = (const float*)d_in[5];
    const float* lnw   = (const float*)d_in[6];
    const float* lnb   = (const float*)d_in[7];
    float* out = (float*)d_out;
    float* ws  = (float*)d_ws;

    float* kv  = ws;
    float* whT = ws + 512;
    float* wpT = ws + 512 + 24576;
    unsigned short* hid = (unsigned short*)(ws + 40960);        // [4][384][66][256] bf16
    unsigned short* qkv = hid + (size_t)4 * 384 * HSZ2;         // [4][384][256][64] bf16

    k_prep<<<dim3(130), dim3(256), 0, stream>>>(prior, wk, wh, wp, kv, whT, wpT);
    for (int slab = 0; slab < 4; ++slab) {
        int r0 = slab * SLAB;
        k2_hidden<<<dim3(HROWS, 4, 8), dim3(256), 0, stream>>>(x, whT, kv, hid, r0);
        k3_dw<<<dim3(8, 192, 4), dim3(256), 0, stream>>>(hid, wdw, qkv);
        kC_patch<<<dim3(256, 4), dim3(256), 0, stream>>>(qkv, wpT, lnw, lnb, out, r0);
    }
}

// Round 14
// 651.019 us; speedup vs baseline: 1.0135x; 1.0135x over previous
//
#include <hip/hip_runtime.h>

// FSAS slab pipeline, 4 slabs of 64 rows, bf16 intermediates.
//   k2 v9: c-OUTER loop, acc[48] (xv ds_read once per c: 64 ds_reads vs 192;
//          weights = contiguous 48-float scalar run per c -> s_load_dwordx16
//          batches, fewer lgkmcnt stalls). Order per output still c-ascending
//          -> bitwise-identical hid.
//   k3 v2: 32-row x 64-col tiles. ~35 us/slab.
//   kC v4: q streamed per-iy (peak regs ~130), bounds-2. ~56 us/slab.
// Workspace:
//   kv  fp32 @ 0      (512)
//   whT fp32 @ 512    (24576)  whT[c*384+o] = w_hidden[o][c]
//   wpT fp32 @ 25088  (8192)   wpT[c*64+o]  = w_proj[o][c]
//   hid bf16 @ float-ofs 40960 : [4][384][66][256]  (51.9 MB)
//   qkv bf16 after hid          : [4][384][256][64]  (50.3 MB)
// Total 102,400,000 B = 97.66 MiB (< proven 99.15 MiB).

#define HW    65536
#define SLAB  64
#define HROWS 66
#define HSZ2  (HROWS*256)   // bf16 elems per (b,ch) hid plane
#define QS    16384         // bf16 elems per (b,ch) qkv plane (256 patches * 64)

__device__ __forceinline__ unsigned short f2bf(float f) {
    unsigned u = __float_as_uint(f);
    u += 0x7FFFu + ((u >> 16) & 1u);       // RNE
    return (unsigned short)(u >> 16);
}
__device__ __forceinline__ float bflo(unsigned u) { return __uint_as_float(u << 16); }
__device__ __forceinline__ float bfhi(unsigned u) { return __uint_as_float(u & 0xFFFF0000u); }

__global__ void k_prep(const float* __restrict__ prior, const float* __restrict__ wk,
                       const float* __restrict__ wh, const float* __restrict__ wp,
                       float* __restrict__ kv, float* __restrict__ whT, float* __restrict__ wpT) {
    int t = blockIdx.x * 256 + threadIdx.x;
    if (t < 512) {
        int b = t >> 7, k = t & 127;
        const float* p = prior + b * 192;
        const float* w = wk + k * 192;
        float s = 0.f;
        for (int f = 0; f < 192; ++f) s = fmaf(p[f], w[f], s);
        kv[t] = s;
        return;
    }
    t -= 512;
    if (t < 24576) {
        int c = t / 384, o = t - c * 384;
        whT[t] = wh[o * 64 + c];
        return;
    }
    t -= 24576;
    int c = t >> 6, o = t & 63;
    wpT[t] = wp[o * 128 + c];
}

// v9: block = (row, col-quarter, b*2+half). Stage xp[64ch][64px] in LDS, then
// wave wv computes out-ch half*192 + wv*48 .. +47 with acc[48], c-outer:
// per c = 1 ds_read (xv) + 48 contiguous scalar weight floats (dwordx16 x3)
// + 48 FMA. 64 ds_reads total (was 192).
__global__ __launch_bounds__(256, 4) void k2_hidden(const float* __restrict__ x,
    const float* __restrict__ whT, const float* __restrict__ kv,
    unsigned short* __restrict__ hid, int r0) {
    __shared__ float sXp[64 * 64];   // 16 KB
    int t = threadIdx.x;
    int row = blockIdx.x;            // 0..65
    int colq = blockIdx.y;           // 0..3
    int z = blockIdx.z;              // 0..7
    int b = z >> 1;
    int half = z & 1;
    int col0 = colq * 64;
    int g = r0 - 1 + row;
    int px = t & 63;
    int wv = __builtin_amdgcn_readfirstlane(t >> 6);   // SGPR -> scalar weight path
    int och0 = half * 192 + wv * 48;
    unsigned short* hb = hid + ((size_t)(b * 384 + och0)) * HSZ2
                         + row * 256 + col0 + px;
    if (g < 0 || g > 255) {          // block-uniform edge path (no barrier here)
        #pragma unroll
        for (int j = 0; j < 48; ++j)
            hb[(size_t)j * HSZ2] = 0;
        return;
    }
    const float* kv1 = kv + b * 128;
    const float* kv2 = kv1 + 64;
    const float2* xb = (const float2*)(x + (size_t)b * 64 * HW + (size_t)g * 256 + col0);
    #pragma unroll
    for (int i = 0; i < 8; ++i) {    // 2048 float2 = 64ch x 32
        int idx = t + i * 256;
        int c = idx >> 5;            // 0..63
        int l2 = idx & 31;
        float2 xv = xb[(size_t)c * (HW / 2) + l2];
        float2 s;
        s.x = fmaf(xv.x, kv1[c], kv2[c]);
        s.y = fmaf(xv.y, kv1[c], kv2[c]);
        *(float2*)&sXp[c * 64 + l2 * 2] = s;
    }
    __syncthreads();
    const float* wbase = whT + och0;                 // SGPR-uniform
    float acc[48];
    #pragma unroll
    for (int j = 0; j < 48; ++j) acc[j] = 0.f;
    #pragma unroll 2
    for (int c = 0; c < 64; ++c) {
        float xv = sXp[c * 64 + px];                 // 1 ds_read per c
        const float* wr = wbase + c * 384;           // 48 contiguous floats, scalar
        #pragma unroll
        for (int j = 0; j < 48; ++j)
            acc[j] = fmaf(wr[j], xv, acc[j]);
    }
    #pragma unroll
    for (int j = 0; j < 48; ++j)
        hb[(size_t)j * HSZ2] = f2bf(acc[j]);
}

// grouped 3x3 conv from bf16 hid -> bf16 qkv patchified [ch][patch][py*8+px]
// v2: 32-row x 64-col tile per block (halo 34x66), 4 pp-passes, 288 fma/thread.
__global__ __launch_bounds__(256) void k3_dw(const unsigned short* __restrict__ hid,
    const float* __restrict__ wdw, unsigned short* __restrict__ qkv) {
    __shared__ float sIn[2 * 34 * 66];
    int t = threadIdx.x;
    int bid = blockIdx.x;            // 8 tiles: tx 0..3 (x64 cols), ty 0..1 (x32 rows)
    int gl = blockIdx.y;             // 0..191
    int b = blockIdx.z;
    int tx = bid & 3, ty = bid >> 2;
    int x0 = tx * 64, y0 = ty * 32;
    const unsigned short* hbase = hid + ((size_t)(b * 384 + 2 * gl)) * HSZ2;
    for (int idx = t; idx < 2 * 34 * 66; idx += 256) {
        int chl = idx >= 2244;
        int rem = idx - chl * 2244;
        int row = rem / 66;
        int col = rem - row * 66;
        int gx = x0 + col - 1;
        float v = 0.f;
        if (gx >= 0 && gx < 256)
            v = bflo((unsigned)hbase[(size_t)chl * HSZ2 + (y0 + row) * 256 + gx]);
        sIn[idx] = v;
    }
    __syncthreads();
    int og = 2 * gl;
    float w0[18], w1[18];
    #pragma unroll
    for (int i = 0; i < 18; ++i) {
        w0[i] = wdw[(size_t)og * 18 + i];
        w1[i] = wdw[(size_t)(og + 1) * 18 + i];
    }
    unsigned short* q0 = qkv + ((size_t)(b * 384 + og)) * QS;
    #pragma unroll
    for (int pp = 0; pp < 4; ++pp) {
        int ly = pp * 8 + (t >> 5);                  // 0..31
        int lxp = (t & 31) * 2;                      // even col in tile
        float a[2][2];                               // [px][out-ch]
        #pragma unroll
        for (int px = 0; px < 2; ++px) {
            float s0 = 0.f, s1 = 0.f;
            #pragma unroll
            for (int i = 0; i < 2; ++i)
                #pragma unroll
                for (int ky = 0; ky < 3; ++ky)
                    #pragma unroll
                    for (int kx = 0; kx < 3; ++kx) {
                        float v = sIn[i * 2244 + (ly + ky) * 66 + (lxp + px + kx)];
                        s0 = fmaf(w0[i * 9 + ky * 3 + kx], v, s0);
                        s1 = fmaf(w1[i * 9 + ky * 3 + kx], v, s1);
                    }
            a[px][0] = s0; a[px][1] = s1;
        }
        int row = y0 + ly;                           // slab row 0..63
        int gx = x0 + lxp;
        int patch = (row >> 3) * 32 + (gx >> 3);     // 0..255
        int off = patch * 64 + (row & 7) * 8 + (gx & 7);   // even
        ((unsigned*)(q0 + off))[0] =
            (unsigned)f2bf(a[0][0]) | ((unsigned)f2bf(a[1][0]) << 16);
        ((unsigned*)(q0 + QS + off))[0] =
            (unsigned)f2bf(a[0][1]) | ((unsigned)f2bf(a[1][1]) << 16);
    }
}

// Fused per-patch: circular conv + LN(128) + *v + proj 128->64.
// Thread t: channel c = t&127, py-half pyh = t>>7.
// v4: q streamed per-iy (k[64] held pre-rotated); 3 barriers, no serial phase.
__global__ __launch_bounds__(256, 2) void kC_patch(const unsigned short* __restrict__ qkv,
    const float* __restrict__ wpT, const float* __restrict__ lnw,
    const float* __restrict__ lnb, float* __restrict__ outp, int r0) {
    __shared__ __align__(16) float sBuf[128 * 68];   // P0/P1: sC[c][68]; P3/P4: sT[pix][132]
    __shared__ __align__(16) float sMu[64];
    __shared__ __align__(16) float sRstd[64];
    int t = threadIdx.x;
    int p = blockIdx.x;              // slab-local patch 0..255
    int b = blockIdx.y;
    int c = t & 127;
    int pyh = t >> 7;

    const uint4* gq = (const uint4*)(qkv + ((size_t)(b * 384 + c)) * QS + p * 64);
    const uint4* gk = (const uint4*)(qkv + ((size_t)(b * 384 + 128 + c)) * QS + p * 64);
    // k rows pre-rotated: reg row s = global row (s + 4*pyh)&7 ; one uint4 per row
    float k[64];
    #pragma unroll
    for (int s = 0; s < 8; ++s) {
        int r = (s + 4 * pyh) & 7;
        uint4 u = gk[r];
        k[s * 8 + 0] = bflo(u.x); k[s * 8 + 1] = bfhi(u.x);
        k[s * 8 + 2] = bflo(u.y); k[s * 8 + 3] = bfhi(u.y);
        k[s * 8 + 4] = bflo(u.z); k[s * 8 + 5] = bfhi(u.z);
        k[s * 8 + 6] = bflo(u.w); k[s * 8 + 7] = bfhi(u.w);
    }
    float acc[4][8];
    #pragma unroll
    for (int it = 0; it < 4; ++it)
        #pragma unroll
        for (int px = 0; px < 8; ++px) acc[it][px] = 0.f;
    // conv: stream one q-row (8 bf16 = 1 uint4) per iy — peak regs ~130 not ~200.
    #pragma unroll
    for (int iy = 0; iy < 8; ++iy) {
        uint4 uq = gq[iy];
        float qr[8];
        qr[0] = bflo(uq.x); qr[1] = bfhi(uq.x);
        qr[2] = bflo(uq.y); qr[3] = bfhi(uq.y);
        qr[4] = bflo(uq.z); qr[5] = bfhi(uq.z);
        qr[6] = bflo(uq.w); qr[7] = bfhi(uq.w);
        #pragma unroll
        for (int ix = 0; ix < 8; ++ix) {
            float qv = qr[ix];
            #pragma unroll
            for (int it = 0; it < 4; ++it) {
                int ks = (it - iy) & 7;              // compile-time
                #pragma unroll
                for (int px = 0; px < 8; ++px)
                    acc[it][px] = fmaf(qv, k[ks * 8 + ((px - ix) & 7)], acc[it][px]);
            }
        }
    }
    // transposed conv scratch: sC[c][pix], pad 68 (row stride 272 B, 16B-aligned)
    #pragma unroll
    for (int it = 0; it < 4; ++it) {
        int pix0 = pyh * 32 + it * 8;
        *(float4*)&sBuf[c * 68 + pix0] =
            make_float4(acc[it][0], acc[it][1], acc[it][2], acc[it][3]);
        *(float4*)&sBuf[c * 68 + pix0 + 4] =
            make_float4(acc[it][4], acc[it][5], acc[it][6], acc[it][7]);
    }
    // prefetch v (32 bf16 = 4 uint4)
    const uint4* gv = (const uint4*)(qkv + ((size_t)(b * 384 + 256 + c)) * QS
                                     + p * 64 + pyh * 32);
    float vv[32];
    #pragma unroll
    for (int f = 0; f < 4; ++f) {
        uint4 u = gv[f];
        vv[f * 8 + 0] = bflo(u.x); vv[f * 8 + 1] = bfhi(u.x);
        vv[f * 8 + 2] = bflo(u.y); vv[f * 8 + 3] = bfhi(u.y);
        vv[f * 8 + 4] = bflo(u.z); vv[f * 8 + 5] = bfhi(u.z);
        vv[f * 8 + 6] = bflo(u.w); vv[f * 8 + 7] = bfhi(u.w);
    }
    float lw = lnw[c], lb = lnb[c];
    __syncthreads();

    // P1: per-pixel channel reduction. Wave w owns pixels w*16..w*16+15;
    // lane bits 4..5 = channel-quarter -> butterfly within the wave.
    {
        int q4 = (t >> 4) & 3;
        int px = (t & 15) | ((t >> 6) << 4);
        float s = 0.f, s2 = 0.f;
        #pragma unroll
        for (int j = 0; j < 32; ++j) {
            float v = sBuf[(q4 * 32 + j) * 68 + px];
            s += v;
            s2 = fmaf(v, v, s2);
        }
        s  += __shfl_xor(s, 16);   s2 += __shfl_xor(s2, 16);
        s  += __shfl_xor(s, 32);   s2 += __shfl_xor(s2, 32);
        if ((t & 48) == 0) {
            float mu = s * (1.f / 128.f);
            float var = s2 * (1.f / 128.f) - mu * mu;
            sMu[px] = mu;
            sRstd[px] = rsqrtf(var + 1e-5f);
        }
    }
    __syncthreads();
    // P3: normalize from acc regs, * v, stage tvv as sT[pix][132] (c contiguous)
    #pragma unroll
    for (int it = 0; it < 4; ++it) {
        int pix0 = pyh * 32 + it * 8;
        float4 ma = *(const float4*)&sMu[pix0];
        float4 mb = *(const float4*)&sMu[pix0 + 4];
        float4 ra = *(const float4*)&sRstd[pix0];
        float4 rb = *(const float4*)&sRstd[pix0 + 4];
        float mus[8] = {ma.x, ma.y, ma.z, ma.w, mb.x, mb.y, mb.z, mb.w};
        float rss[8] = {ra.x, ra.y, ra.z, ra.w, rb.x, rb.y, rb.z, rb.w};
        #pragma unroll
        for (int px = 0; px < 8; ++px) {
            float tv = fmaf((acc[it][px] - mus[px]) * rss[px], lw, lb)
                       * vv[it * 8 + px];
            sBuf[(pix0 + px) * 132 + c] = tv;
        }
    }
    __syncthreads();
    // P4: proj 128->64, tvv read as float4 (4 channels / ds_read_b128)
    {
        int px = t & 63;
        int og = __builtin_amdgcn_readfirstlane((t >> 6) * 16);
        float po[16];
        #pragma unroll
        for (int j = 0; j < 16; ++j) po[j] = 0.f;
        const float4* tb = (const float4*)&sBuf[px * 132];
        #pragma unroll 4
        for (int k4 = 0; k4 < 32; ++k4) {
            float4 tv = tb[k4];
            const float* w0 = wpT + (k4 * 4 + 0) * 64 + og;
            const float* w1 = wpT + (k4 * 4 + 1) * 64 + og;
            const float* w2 = wpT + (k4 * 4 + 2) * 64 + og;
            const float* w3 = wpT + (k4 * 4 + 3) * 64 + og;
            #pragma unroll
            for (int j = 0; j < 16; ++j)
                po[j] = fmaf(w0[j], tv.x,
                        fmaf(w1[j], tv.y,
                        fmaf(w2[j], tv.z,
                        fmaf(w3[j], tv.w, po[j]))));
        }
        int grow = r0 + (p >> 5) * 8 + (px >> 3);
        int gcol = (p & 31) * 8 + (px & 7);
        float* ob = outp + ((size_t)(b * 64 + og)) * HW + grow * 256 + gcol;
        #pragma unroll
        for (int j = 0; j < 16; ++j) ob[(size_t)j * HW] = po[j];
    }
}

extern "C" void kernel_launch(void* const* d_in, const int* in_sizes, int n_in,
                              void* d_out, int out_size, void* d_ws, size_t ws_size,
                              hipStream_t stream) {
    const float* x     = (const float*)d_in[0];
    const float* prior = (const float*)d_in[1];
    const float* wk    = (const float*)d_in[2];
    const float* wh    = (const float*)d_in[3];
    const float* wdw   = (const float*)d_in[4];
    const float* wp    = (const float*)d_in[5];
    const float* lnw   = (const float*)d_in[6];
    const float* lnb   = (const float*)d_in[7];
    float* out = (float*)d_out;
    float* ws  = (float*)d_ws;

    float* kv  = ws;
    float* whT = ws + 512;
    float* wpT = ws + 512 + 24576;
    unsigned short* hid = (unsigned short*)(ws + 40960);        // [4][384][66][256] bf16
    unsigned short* qkv = hid + (size_t)4 * 384 * HSZ2;         // [4][384][256][64] bf16

    k_prep<<<dim3(130), dim3(256), 0, stream>>>(prior, wk, wh, wp, kv, whT, wpT);
    for (int slab = 0; slab < 4; ++slab) {
        int r0 = slab * SLAB;
        k2_hidden<<<dim3(HROWS, 4, 8), dim3(256), 0, stream>>>(x, whT, kv, hid, r0);
        k3_dw<<<dim3(8, 192, 4), dim3(256), 0, stream>>>(hid, wdw, qkv);
        kC_patch<<<dim3(256, 4), dim3(256), 0, stream>>>(qkv, wpT, lnw, lnb, out, r0);
    }
}

// Round 15
// 593.787 us; speedup vs baseline: 1.1112x; 1.0964x over previous
//
#include <hip/hip_runtime.h>

// FSAS slab pipeline, 4 slabs of 64 rows, bf16 intermediates.
//   k2 v10: c-outer acc[24] per wave (96 och/block, grid.z=b*4+quarter),
//          launch_bounds(256,8) -> 8 waves/SIMD to cover the per-c scalar
//          lgkmcnt(0) drain (SMEM is out-of-order; VALUBusy pinned ~46% at
//          4 waves across v2/v7/v9). c-order unchanged -> bitwise-same hid.
//   k3 v3: division-free staging (interior as uint pairs, halo separate).
//   kC v4: q streamed per-iy (peak regs ~130), bounds-2. ~52-56 us/slab.
// Workspace:
//   kv  fp32 @ 0      (512)
//   whT fp32 @ 512    (24576)  whT[c*384+o] = w_hidden[o][c]
//   wpT fp32 @ 25088  (8192)   wpT[c*64+o]  = w_proj[o][c]
//   hid bf16 @ float-ofs 40960 : [4][384][66][256]  (51.9 MB)
//   qkv bf16 after hid          : [4][384][256][64]  (50.3 MB)
// Total 102,400,000 B = 97.66 MiB (< proven 99.15 MiB).

#define HW    65536
#define SLAB  64
#define HROWS 66
#define HSZ2  (HROWS*256)   // bf16 elems per (b,ch) hid plane
#define QS    16384         // bf16 elems per (b,ch) qkv plane (256 patches * 64)

__device__ __forceinline__ unsigned short f2bf(float f) {
    unsigned u = __float_as_uint(f);
    u += 0x7FFFu + ((u >> 16) & 1u);       // RNE
    return (unsigned short)(u >> 16);
}
__device__ __forceinline__ float bflo(unsigned u) { return __uint_as_float(u << 16); }
__device__ __forceinline__ float bfhi(unsigned u) { return __uint_as_float(u & 0xFFFF0000u); }

__global__ void k_prep(const float* __restrict__ prior, const float* __restrict__ wk,
                       const float* __restrict__ wh, const float* __restrict__ wp,
                       float* __restrict__ kv, float* __restrict__ whT, float* __restrict__ wpT) {
    int t = blockIdx.x * 256 + threadIdx.x;
    if (t < 512) {
        int b = t >> 7, k = t & 127;
        const float* p = prior + b * 192;
        const float* w = wk + k * 192;
        float s = 0.f;
        for (int f = 0; f < 192; ++f) s = fmaf(p[f], w[f], s);
        kv[t] = s;
        return;
    }
    t -= 512;
    if (t < 24576) {
        int c = t / 384, o = t - c * 384;
        whT[t] = wh[o * 64 + c];
        return;
    }
    t -= 24576;
    int c = t >> 6, o = t & 63;
    wpT[t] = wp[o * 128 + c];
}

// v10: block = (row, col-quarter, b*4+och-quarter). Stage xp[64ch][64px] in
// LDS, then wave wv computes out-ch quarter*96 + wv*24 .. +23 with acc[24],
// c-outer. 8 waves/SIMD (bounds 256,8): unified regs ~50 fit the 64-reg/wave
// budget; 32 waves/CU cover the per-c scalar-load drain.
__global__ __launch_bounds__(256, 8) void k2_hidden(const float* __restrict__ x,
    const float* __restrict__ whT, const float* __restrict__ kv,
    unsigned short* __restrict__ hid, int r0) {
    __shared__ float sXp[64 * 64];   // 16 KB
    int t = threadIdx.x;
    int row = blockIdx.x;            // 0..65
    int colq = blockIdx.y;           // 0..3
    int z = blockIdx.z;              // 0..15
    int b = z >> 2;
    int oq = z & 3;
    int col0 = colq * 64;
    int g = r0 - 1 + row;
    int px = t & 63;
    int wv = __builtin_amdgcn_readfirstlane(t >> 6);   // SGPR -> scalar weight path
    int och0 = oq * 96 + wv * 24;
    unsigned short* hb = hid + ((size_t)(b * 384 + och0)) * HSZ2
                         + row * 256 + col0 + px;
    if (g < 0 || g > 255) {          // block-uniform edge path (no barrier here)
        #pragma unroll
        for (int j = 0; j < 24; ++j)
            hb[(size_t)j * HSZ2] = 0;
        return;
    }
    const float* kv1 = kv + b * 128;
    const float* kv2 = kv1 + 64;
    const float2* xb = (const float2*)(x + (size_t)b * 64 * HW + (size_t)g * 256 + col0);
    #pragma unroll
    for (int i = 0; i < 8; ++i) {    // 2048 float2 = 64ch x 32
        int idx = t + i * 256;
        int c = idx >> 5;            // 0..63
        int l2 = idx & 31;
        float2 xv = xb[(size_t)c * (HW / 2) + l2];
        float2 s;
        s.x = fmaf(xv.x, kv1[c], kv2[c]);
        s.y = fmaf(xv.y, kv1[c], kv2[c]);
        *(float2*)&sXp[c * 64 + l2 * 2] = s;
    }
    __syncthreads();
    const float* wbase = whT + och0;                 // SGPR-uniform
    float acc[24];
    #pragma unroll
    for (int j = 0; j < 24; ++j) acc[j] = 0.f;
    #pragma unroll 2
    for (int c = 0; c < 64; ++c) {
        float xv = sXp[c * 64 + px];                 // 1 ds_read per c
        const float* wr = wbase + c * 384;           // 24 contiguous floats, scalar
        #pragma unroll
        for (int j = 0; j < 24; ++j)
            acc[j] = fmaf(wr[j], xv, acc[j]);
    }
    #pragma unroll
    for (int j = 0; j < 24; ++j)
        hb[(size_t)j * HSZ2] = f2bf(acc[j]);
}

// grouped 3x3 conv from bf16 hid -> bf16 qkv patchified [ch][patch][py*8+px]
// v3: 32-row x 64-col tile; staging division-free: interior 64 cols as uint
// pairs (2176 loads, rowId = idx>>5), halo cols 0/65 by 136 threads.
__global__ __launch_bounds__(256) void k3_dw(const unsigned short* __restrict__ hid,
    const float* __restrict__ wdw, unsigned short* __restrict__ qkv) {
    __shared__ float sIn[2 * 34 * 66];
    int t = threadIdx.x;
    int bid = blockIdx.x;            // 8 tiles: tx 0..3 (x64 cols), ty 0..1 (x32 rows)
    int gl = blockIdx.y;             // 0..191
    int b = blockIdx.z;
    int tx = bid & 3, ty = bid >> 2;
    int x0 = tx * 64, y0 = ty * 32;
    const unsigned short* hbase = hid + ((size_t)(b * 384 + 2 * gl)) * HSZ2;
    // interior: 68 rowIds (2ch x 34row) x 32 uint (cols 1..64) = 2176
    #pragma unroll
    for (int i = 0; i < 9; ++i) {
        int idx = t + i * 256;
        if (idx < 2176) {
            int rowId = idx >> 5;            // 0..67
            int cp = idx & 31;               // 0..31
            int chl = rowId >= 34;
            int r = chl ? rowId - 34 : rowId;
            unsigned u = *(const unsigned*)&hbase[(size_t)chl * HSZ2
                                                  + (y0 + r) * 256 + x0 + cp * 2];
            float* srow = &sIn[chl * 2244 + r * 66];
            srow[1 + cp * 2] = bflo(u);
            srow[2 + cp * 2] = bfhi(u);
        }
    }
    // halo: cols 0 and 65 for 68 rowIds = 136 elements
    if (t < 136) {
        int rowId = t >> 1;
        int side = t & 1;                    // 0 -> col 0 (gx = x0-1), 1 -> col 65 (gx = x0+64)
        int chl = rowId >= 34;
        int r = chl ? rowId - 34 : rowId;
        int col = side ? 65 : 0;
        int gx = x0 + col - 1;
        float v = 0.f;
        if (gx >= 0 && gx < 256)
            v = bflo((unsigned)hbase[(size_t)chl * HSZ2 + (y0 + r) * 256 + gx]);
        sIn[chl * 2244 + r * 66 + col] = v;
    }
    __syncthreads();
    int og = 2 * gl;
    float w0[18], w1[18];
    #pragma unroll
    for (int i = 0; i < 18; ++i) {
        w0[i] = wdw[(size_t)og * 18 + i];
        w1[i] = wdw[(size_t)(og + 1) * 18 + i];
    }
    unsigned short* q0 = qkv + ((size_t)(b * 384 + og)) * QS;
    #pragma unroll
    for (int pp = 0; pp < 4; ++pp) {
        int ly = pp * 8 + (t >> 5);                  // 0..31
        int lxp = (t & 31) * 2;                      // even col in tile
        float a[2][2];                               // [px][out-ch]
        #pragma unroll
        for (int px = 0; px < 2; ++px) {
            float s0 = 0.f, s1 = 0.f;
            #pragma unroll
            for (int i = 0; i < 2; ++i)
                #pragma unroll
                for (int ky = 0; ky < 3; ++ky)
                    #pragma unroll
                    for (int kx = 0; kx < 3; ++kx) {
                        float v = sIn[i * 2244 + (ly + ky) * 66 + (lxp + px + kx)];
                        s0 = fmaf(w0[i * 9 + ky * 3 + kx], v, s0);
                        s1 = fmaf(w1[i * 9 + ky * 3 + kx], v, s1);
                    }
            a[px][0] = s0; a[px][1] = s1;
        }
        int row = y0 + ly;                           // slab row 0..63
        int gx = x0 + lxp;
        int patch = (row >> 3) * 32 + (gx >> 3);     // 0..255
        int off = patch * 64 + (row & 7) * 8 + (gx & 7);   // even
        ((unsigned*)(q0 + off))[0] =
            (unsigned)f2bf(a[0][0]) | ((unsigned)f2bf(a[1][0]) << 16);
        ((unsigned*)(q0 + QS + off))[0] =
            (unsigned)f2bf(a[0][1]) | ((unsigned)f2bf(a[1][1]) << 16);
    }
}

// Fused per-patch: circular conv + LN(128) + *v + proj 128->64.
// Thread t: channel c = t&127, py-half pyh = t>>7.
// v4: q streamed per-iy (k[64] held pre-rotated); 3 barriers, no serial phase.
__global__ __launch_bounds__(256, 2) void kC_patch(const unsigned short* __restrict__ qkv,
    const float* __restrict__ wpT, const float* __restrict__ lnw,
    const float* __restrict__ lnb, float* __restrict__ outp, int r0) {
    __shared__ __align__(16) float sBuf[128 * 68];   // P0/P1: sC[c][68]; P3/P4: sT[pix][132]
    __shared__ __align__(16) float sMu[64];
    __shared__ __align__(16) float sRstd[64];
    int t = threadIdx.x;
    int p = blockIdx.x;              // slab-local patch 0..255
    int b = blockIdx.y;
    int c = t & 127;
    int pyh = t >> 7;

    const uint4* gq = (const uint4*)(qkv + ((size_t)(b * 384 + c)) * QS + p * 64);
    const uint4* gk = (const uint4*)(qkv + ((size_t)(b * 384 + 128 + c)) * QS + p * 64);
    // k rows pre-rotated: reg row s = global row (s + 4*pyh)&7 ; one uint4 per row
    float k[64];
    #pragma unroll
    for (int s = 0; s < 8; ++s) {
        int r = (s + 4 * pyh) & 7;
        uint4 u = gk[r];
        k[s * 8 + 0] = bflo(u.x); k[s * 8 + 1] = bfhi(u.x);
        k[s * 8 + 2] = bflo(u.y); k[s * 8 + 3] = bfhi(u.y);
        k[s * 8 + 4] = bflo(u.z); k[s * 8 + 5] = bfhi(u.z);
        k[s * 8 + 6] = bflo(u.w); k[s * 8 + 7] = bfhi(u.w);
    }
    float acc[4][8];
    #pragma unroll
    for (int it = 0; it < 4; ++it)
        #pragma unroll
        for (int px = 0; px < 8; ++px) acc[it][px] = 0.f;
    // conv: stream one q-row (8 bf16 = 1 uint4) per iy — peak regs ~130 not ~200.
    #pragma unroll
    for (int iy = 0; iy < 8; ++iy) {
        uint4 uq = gq[iy];
        float qr[8];
        qr[0] = bflo(uq.x); qr[1] = bfhi(uq.x);
        qr[2] = bflo(uq.y); qr[3] = bfhi(uq.y);
        qr[4] = bflo(uq.z); qr[5] = bfhi(uq.z);
        qr[6] = bflo(uq.w); qr[7] = bfhi(uq.w);
        #pragma unroll
        for (int ix = 0; ix < 8; ++ix) {
            float qv = qr[ix];
            #pragma unroll
            for (int it = 0; it < 4; ++it) {
                int ks = (it - iy) & 7;              // compile-time
                #pragma unroll
                for (int px = 0; px < 8; ++px)
                    acc[it][px] = fmaf(qv, k[ks * 8 + ((px - ix) & 7)], acc[it][px]);
            }
        }
    }
    // transposed conv scratch: sC[c][pix], pad 68 (row stride 272 B, 16B-aligned)
    #pragma unroll
    for (int it = 0; it < 4; ++it) {
        int pix0 = pyh * 32 + it * 8;
        *(float4*)&sBuf[c * 68 + pix0] =
            make_float4(acc[it][0], acc[it][1], acc[it][2], acc[it][3]);
        *(float4*)&sBuf[c * 68 + pix0 + 4] =
            make_float4(acc[it][4], acc[it][5], acc[it][6], acc[it][7]);
    }
    // prefetch v (32 bf16 = 4 uint4)
    const uint4* gv = (const uint4*)(qkv + ((size_t)(b * 384 + 256 + c)) * QS
                                     + p * 64 + pyh * 32);
    float vv[32];
    #pragma unroll
    for (int f = 0; f < 4; ++f) {
        uint4 u = gv[f];
        vv[f * 8 + 0] = bflo(u.x); vv[f * 8 + 1] = bfhi(u.x);
        vv[f * 8 + 2] = bflo(u.y); vv[f * 8 + 3] = bfhi(u.y);
        vv[f * 8 + 4] = bflo(u.z); vv[f * 8 + 5] = bfhi(u.z);
        vv[f * 8 + 6] = bflo(u.w); vv[f * 8 + 7] = bfhi(u.w);
    }
    float lw = lnw[c], lb = lnb[c];
    __syncthreads();

    // P1: per-pixel channel reduction. Wave w owns pixels w*16..w*16+15;
    // lane bits 4..5 = channel-quarter -> butterfly within the wave.
    {
        int q4 = (t >> 4) & 3;
        int px = (t & 15) | ((t >> 6) << 4);
        float s = 0.f, s2 = 0.f;
        #pragma unroll
        for (int j = 0; j < 32; ++j) {
            float v = sBuf[(q4 * 32 + j) * 68 + px];
            s += v;
            s2 = fmaf(v, v, s2);
        }
        s  += __shfl_xor(s, 16);   s2 += __shfl_xor(s2, 16);
        s  += __shfl_xor(s, 32);   s2 += __shfl_xor(s2, 32);
        if ((t & 48) == 0) {
            float mu = s * (1.f / 128.f);
            float var = s2 * (1.f / 128.f) - mu * mu;
            sMu[px] = mu;
            sRstd[px] = rsqrtf(var + 1e-5f);
        }
    }
    __syncthreads();
    // P3: normalize from acc regs, * v, stage tvv as sT[pix][132] (c contiguous)
    #pragma unroll
    for (int it = 0; it < 4; ++it) {
        int pix0 = pyh * 32 + it * 8;
        float4 ma = *(const float4*)&sMu[pix0];
        float4 mb = *(const float4*)&sMu[pix0 + 4];
        float4 ra = *(const float4*)&sRstd[pix0];
        float4 rb = *(const float4*)&sRstd[pix0 + 4];
        float mus[8] = {ma.x, ma.y, ma.z, ma.w, mb.x, mb.y, mb.z, mb.w};
        float rss[8] = {ra.x, ra.y, ra.z, ra.w, rb.x, rb.y, rb.z, rb.w};
        #pragma unroll
        for (int px = 0; px < 8; ++px) {
            float tv = fmaf((acc[it][px] - mus[px]) * rss[px], lw, lb)
                       * vv[it * 8 + px];
            sBuf[(pix0 + px) * 132 + c] = tv;
        }
    }
    __syncthreads();
    // P4: proj 128->64, tvv read as float4 (4 channels / ds_read_b128)
    {
        int px = t & 63;
        int og = __builtin_amdgcn_readfirstlane((t >> 6) * 16);
        float po[16];
        #pragma unroll
        for (int j = 0; j < 16; ++j) po[j] = 0.f;
        const float4* tb = (const float4*)&sBuf[px * 132];
        #pragma unroll 4
        for (int k4 = 0; k4 < 32; ++k4) {
            float4 tv = tb[k4];
            const float* w0 = wpT + (k4 * 4 + 0) * 64 + og;
            const float* w1 = wpT + (k4 * 4 + 1) * 64 + og;
            const float* w2 = wpT + (k4 * 4 + 2) * 64 + og;
            const float* w3 = wpT + (k4 * 4 + 3) * 64 + og;
            #pragma unroll
            for (int j = 0; j < 16; ++j)
                po[j] = fmaf(w0[j], tv.x,
                        fmaf(w1[j], tv.y,
                        fmaf(w2[j], tv.z,
                        fmaf(w3[j], tv.w, po[j]))));
        }
        int grow = r0 + (p >> 5) * 8 + (px >> 3);
        int gcol = (p & 31) * 8 + (px & 7);
        float* ob = outp + ((size_t)(b * 64 + og)) * HW + grow * 256 + gcol;
        #pragma unroll
        for (int j = 0; j < 16; ++j) ob[(size_t)j * HW] = po[j];
    }
}

extern "C" void kernel_launch(void* const* d_in, const int* in_sizes, int n_in,
                              void* d_out, int out_size, void* d_ws, size_t ws_size,
                              hipStream_t stream) {
    const float* x     = (const float*)d_in[0];
    const float* prior = (const float*)d_in[1];
    const float* wk    = (const float*)d_in[2];
    const float* wh    = (const float*)d_in[3];
    const float* wdw   = (const float*)d_in[4];
    const float* wp    = (const float*)d_in[5];
    const float* lnw   = (const float*)d_in[6];
    const float* lnb   = (const float*)d_in[7];
    float* out = (float*)d_out;
    float* ws  = (float*)d_ws;

    float* kv  = ws;
    float* whT = ws + 512;
    float* wpT = ws + 512 + 24576;
    unsigned short* hid = (unsigned short*)(ws + 40960);        // [4][384][66][256] bf16
    unsigned short* qkv = hid + (size_t)4 * 384 * HSZ2;         // [4][384][256][64] bf16

    k_prep<<<dim3(130), dim3(256), 0, stream>>>(prior, wk, wh, wp, kv, whT, wpT);
    for (int slab = 0; slab < 4; ++slab) {
        int r0 = slab * SLAB;
        k2_hidden<<<dim3(HROWS, 4, 16), dim3(256), 0, stream>>>(x, whT, kv, hid, r0);
        k3_dw<<<dim3(8, 192, 4), dim3(256), 0, stream>>>(hid, wdw, qkv);
        kC_patch<<<dim3(256, 4), dim3(256), 0, stream>>>(qkv, wpT, lnw, lnb, out, r0);
    }
}